// Round 14
// baseline (3242.883 us; speedup 1.0000x reference)
//
#include <hip/hip_runtime.h>
#include <cstdint>
#include <cstddef>

// Problem constants
#define B_   1024
#define T_   200
#define I_   64
#define H_   512
#define HID_ 256
#define LDA_ 1024   // state row: [h(512) | c(512)]  (x read direct from input)
#define NFRAG 88    // W frags per j-tile: 4 gates * 18 kk + 16 d kk
#define NBUF 12     // state rotation depth (addresses unique for 12 steps)
#define RINV 8      // joint-fence period; NBUF >= RINV + drift + slack

typedef __bf16 bf16;
typedef __bf16 bf16x8 __attribute__((ext_vector_type(8)));
typedef float  f32x4  __attribute__((ext_vector_type(4)));

__device__ inline void gload_lds16(const bf16* g, void* l) {
  void* gg = (void*)g;
  __builtin_amdgcn_global_load_lds((__attribute__((address_space(1))) void*)gg,
                                   (__attribute__((address_space(3))) void*)l,
                                   16, 0, 0);
}

__device__ inline float sigm(float x) { return 1.f / (1.f + __expf(-x)); }
__device__ inline float tanh_f(float x) {
  float e = __expf(2.f * fabsf(x));
  float r = 1.f - 2.f / (e + 1.f);
  return copysignf(r, x);
}
__device__ inline uint32_t bf16bits(float v) {
  union { bf16 h; unsigned short u; } cv; cv.h = (bf16)v; return (uint32_t)cv.u;
}

// ---------------------------------------------------------------------------
// Persistent TimeLSTM — TWO independent 64-row pipelines per CU.
// 256 blocks x 512 threads (8 waves, 2/SIMD), 1 block/CU.
// Block bid: mt8 = bid&7, jt = bid>>3. Waves 0-3 = cluster 0 (group 2*mt8),
// waves 4-7 = cluster 1 (group 2*mt8+1). Group g owns rows g*64..+64; its 32
// clusters (one per jt) exchange h/c each step. Clusters share the block's W
// LDS image (same jt). While one cluster waits on its sync round-trip (HBM),
// the other cluster's waves keep the SIMDs busy.
//
// Per-cluster sync = r10-proven protocol (1 poller, monolithic wait):
//  - state writes: agent-scope relaxed atomic stores (write-through)
//  - publish: each wave drains own stores (vmcnt 0), lane0 bumps a monotonic
//    LDS counter; the 4th arrival for step t stores flags[g*32+jt] = t+1
//  - wait: poller wave (wi==0) polls its 32 group flags, then releases
//    siblings via an LDS go-word (CU-local, no LLC traffic)
//  - joint fence every RINV steps: all 8 waves __syncthreads, tid0
//    fence(acquire,"agent") [L1+L2 inv], __syncthreads. Rotation staleness:
//    a reused slot's stale line was filled >= NBUF=12 steps ago; the last
//    joint fence is <= RINV-1=7 steps ago (each cluster fences at its own
//    t%8==0, jointly) => invalidated before reuse.
// Overwrite safety: writes to slot nxt at step t happen only after flags>=t
// (all peers finished step t-1; slot nxt's readers ran at step t-11).
// Intra-cluster wave skew <=1 step: step t+1's wait needs own flag t+1,
// which needs all 4 own waves' step-t bumps.
// ---------------------------------------------------------------------------
__global__ __launch_bounds__(512, 2)
void persist(bf16* __restrict__ states,
             const float* __restrict__ x, const float* __restrict__ tsT,
             const bf16* __restrict__ img,
             const float* __restrict__ ba, const float* __restrict__ bu,
             const float* __restrict__ bd, int* __restrict__ flags)
{
  __shared__ __align__(16) bf16 Wl[NFRAG * 512];   // 90112 B
  __shared__ int scnt[2];   // per-cluster monotonic wave arrivals
  __shared__ int gogo[2];   // per-cluster release word (last step granted)

  const int tid = threadIdx.x;
  const int l   = tid & 63, w = tid >> 6;
  const int cl  = w >> 2, wi = w & 3;
  const int bid = blockIdx.x;
  const int mt8 = bid & 7, jt = bid >> 3;
  const int g   = mt8 * 2 + cl;       // this cluster's row group
  const int rw  = g * 64 + wi * 16;   // wave's 16-row band
  const int col = l & 15, kh = l >> 4;
  const size_t SB = (size_t)B_ * LDA_;

  // Load this j-tile's W image (fragment-ordered) into LDS once.
  {
    const bf16* src = img + (size_t)jt * (NFRAG * 512);
#pragma unroll
    for (int it = 0; it < 11; ++it)    // 11 * 8192 B = 90112 B
      gload_lds16(src + it * 4096 + tid * 8, (char*)Wl + it * 8192 + tid * 16);
  }
  if (tid < 2) { scnt[tid] = 0; gogo[tid] = 0; }

  float bg[4], bdv;
#pragma unroll
  for (int gg = 0; gg < 4; ++gg) {
    int n = gg * 512 + jt * 16 + col;
    bg[gg] = ba[n] + bu[n];
  }
  bdv = bd[jt * 16 + col];
  __syncthreads();   // drains gload_lds

  float cst[4] = {0.f, 0.f, 0.f, 0.f};   // cell state for rows kh*4+q, col
  const bf16x8* Wf = (const bf16x8*)Wl;

  int cur = 0, nxt = 1;
  for (int t = 0; t < T_; ++t) {
    const bf16* Ac = states + (size_t)cur * SB;
    bf16*       An = states + (size_t)nxt * SB;

    // --- phase A: immutable-input preloads (overlap the wait) ---
    const int rb = rw + kh * 4;
    float4 tt4 = *(const float4*)(tsT + (size_t)t * B_ + rb);
    bf16x8 ax0, ax1;   // x fragments for kk=16,17 (direct from float input)
    {
      const float* xp = x + ((size_t)(rw + col) * T_ + t) * I_ + kh * 8;
      float4 a0 = *(const float4*)(xp);
      float4 a1 = *(const float4*)(xp + 4);
      float4 b0 = *(const float4*)(xp + 32);
      float4 b1 = *(const float4*)(xp + 36);
      ax0 = (bf16x8){(bf16)a0.x, (bf16)a0.y, (bf16)a0.z, (bf16)a0.w,
                     (bf16)a1.x, (bf16)a1.y, (bf16)a1.z, (bf16)a1.w};
      ax1 = (bf16x8){(bf16)b0.x, (bf16)b0.y, (bf16)b0.z, (bf16)b0.w,
                     (bf16)b1.x, (bf16)b1.y, (bf16)b1.z, (bf16)b1.w};
    }

    // --- phase B: per-cluster wait (poller + LDS release) ---
    if (t > 0) {
      if (wi == 0) {
        const int* fl = flags + g * 32 + (l & 31);
        while (__hip_atomic_load(fl, __ATOMIC_RELAXED,
                                 __HIP_MEMORY_SCOPE_AGENT) < t)
          __builtin_amdgcn_s_sleep(1);
        asm volatile("" ::: "memory");
        if (l == 0)
          __hip_atomic_store(&gogo[cl], t, __ATOMIC_RELEASE,
                             __HIP_MEMORY_SCOPE_WORKGROUP);
      } else {
        while (__hip_atomic_load(&gogo[cl], __ATOMIC_ACQUIRE,
                                 __HIP_MEMORY_SCOPE_WORKGROUP) < t)
          __builtin_amdgcn_s_sleep(1);
        asm volatile("" ::: "memory");
      }
      // joint fence step: block-ordered L1+L2 invalidate (rotation proof)
      if ((t & (RINV - 1)) == 0) {
        __syncthreads();
        if (tid == 0)
          __builtin_amdgcn_fence(__ATOMIC_ACQUIRE, "agent");
        __syncthreads();
      }
    }

    // --- phase C: burst-load A row (h, c) into registers, then MFMA ---
    const size_t ra = (size_t)(rw + col) * LDA_ + kh * 8;

    bf16x8 aregh[16], aregc[16];
#pragma unroll
    for (int kk = 0; kk < 16; ++kk) {
      aregh[kk] = *(const bf16x8*)(Ac + ra + kk * 32);           // h
      aregc[kk] = *(const bf16x8*)(Ac + ra + 512 + kk * 32);     // c
    }

    f32x4 acc[4], accd0, accd1;
#pragma unroll
    for (int gg = 0; gg < 4; ++gg) acc[gg] = (f32x4){bg[gg], bg[gg], bg[gg], bg[gg]};
    accd0 = (f32x4){bdv, bdv, bdv, bdv};
    accd1 = (f32x4){0.f, 0.f, 0.f, 0.f};

    // gates: kk 0..15 from h, kk 16..17 from x
#pragma unroll
    for (int kk = 0; kk < 18; ++kk) {
      bf16x8 a = (kk < 16) ? aregh[kk] : (kk == 16 ? ax0 : ax1);
#pragma unroll
      for (int gg = 0; gg < 4; ++gg) {
        bf16x8 bv = Wf[(gg * 18 + kk) * 64 + l];
        acc[gg] = __builtin_amdgcn_mfma_f32_16x16x32_bf16(a, bv, acc[gg], 0, 0, 0);
      }
    }
    // d: kk 0..15 from c, split accumulator
#pragma unroll
    for (int kk = 0; kk < 16; kk += 2) {
      accd0 = __builtin_amdgcn_mfma_f32_16x16x32_bf16(aregc[kk],     Wf[(72 + kk) * 64 + l], accd0, 0, 0, 0);
      accd1 = __builtin_amdgcn_mfma_f32_16x16x32_bf16(aregc[kk + 1], Wf[(73 + kk) * 64 + l], accd1, 0, 0, 0);
    }

    // --- phase D: gate math + packed agent-atomic state stores ---
#pragma unroll
    for (int q = 0; q < 4; ++q) {
      int row   = rb + q;
      float tt  = (&tt4.x)[q];
      float cs1 = tanh_f(accd0[q] + accd1[q]);
      float cadj = cst[q] - cs1 + cs1 * tt;
      float fg = sigm(acc[0][q]);
      float ig = sigm(acc[1][q]);
      float og = sigm(acc[2][q]);
      float cg_ = sigm(acc[3][q]);
      float cn = fg * cadj + ig * cg_;
      float hn = og * tanh_f(cn);
      cst[q] = cn;

      uint32_t hb = bf16bits(hn), cb = bf16bits(cn);
      uint32_t hb2 = (uint32_t)__shfl_xor((int)hb, 1, 64);
      uint32_t cb2 = (uint32_t)__shfl_xor((int)cb, 1, 64);
      if ((l & 1) == 0) {   // even col owns [col, col+1]
        uint32_t hwd = hb | (hb2 << 16);
        uint32_t cwd = cb | (cb2 << 16);
        uint32_t* hp = (uint32_t*)(An + (size_t)row * LDA_ + jt * 16 + col);
        uint32_t* cp = (uint32_t*)(An + (size_t)row * LDA_ + 512 + jt * 16 + col);
        __hip_atomic_store(hp, hwd, __ATOMIC_RELAXED, __HIP_MEMORY_SCOPE_AGENT);
        __hip_atomic_store(cp, cwd, __ATOMIC_RELAXED, __HIP_MEMORY_SCOPE_AGENT);
      }
    }

    // --- phase E: per-cluster publish (drain, bump, 4th arrival -> flag) ---
    if (t + 1 < T_) {
      asm volatile("s_waitcnt vmcnt(0)" ::: "memory");  // my stores committed
      if (l == 0) {
        int prev = atomicAdd(&scnt[cl], 1);             // LDS, monotonic
        if (prev == 4 * (t + 1) - 1)                    // last of 4 waves
          __hip_atomic_store(flags + g * 32 + jt, t + 1, __ATOMIC_RELAXED,
                             __HIP_MEMORY_SCOPE_AGENT);
      }
    }

    cur = nxt;
    nxt = (nxt + 1 == NBUF) ? 0 : nxt + 1;
  }
}

// ---------------------------------------------------------------------------
// Pack W into per-j-tile images in MFMA B-fragment order.
// ---------------------------------------------------------------------------
__global__ void pack_wimg(const float* __restrict__ Wa, const float* __restrict__ Ua,
                          const float* __restrict__ Wd, bf16* __restrict__ img)
{
  int tid = blockIdx.x * 256 + threadIdx.x;   // (jt*88 + f)*64 + lane
  if (tid >= 32 * NFRAG * 64) return;
  int l  = tid & 63;
  int f  = (tid >> 6) % NFRAG;
  int jt = tid / (NFRAG * 64);
  int col = l & 15, kh = l >> 4;
  float v[8];
  if (f < 72) {
    int g = f / 18, kk = f % 18;
    int n = g * 512 + jt * 16 + col;
    if (kk < 16) {
      int k = kk * 32 + kh * 8;
#pragma unroll
      for (int r = 0; r < 8; ++r) v[r] = Wa[(size_t)n * 512 + k + r];
    } else {
      int k = (kk - 16) * 32 + kh * 8;
#pragma unroll
      for (int r = 0; r < 8; ++r) v[r] = Ua[(size_t)n * 64 + k + r];
    }
  } else {
    int kk = f - 72;
    int n = jt * 16 + col;
    int k = kk * 32 + kh * 8;
#pragma unroll
    for (int r = 0; r < 8; ++r) v[r] = Wd[(size_t)n * 512 + k + r];
  }
  bf16* dst = img + (size_t)tid * 8;
#pragma unroll
  for (int r = 0; r < 8; ++r) dst[r] = (bf16)v[r];
}

__global__ void pack_w1(const float* __restrict__ W1, bf16* __restrict__ W1b)
{
  int idx = blockIdx.x * 256 + threadIdx.x;
  if (idx < HID_ * H_) W1b[idx] = (bf16)W1[idx];
}

// init: state buf 0 (h=0, c=0), ts transpose, flag zeroing
__global__ void init_state(const float* __restrict__ x, const float* __restrict__ ts,
                           bf16* __restrict__ states, float* __restrict__ tsT,
                           int* __restrict__ flags)
{
  int idx = blockIdx.x * 256 + threadIdx.x;
  if (idx < 16 * 32) flags[idx] = 0;
  if (idx < B_ * T_) {
    int b = idx / T_, t = idx - b * T_;
    tsT[(size_t)t * B_ + b] = ts[idx];
  }
  if (idx >= B_ * LDA_) return;
  states[idx] = (bf16)0.f;   // h0 = c0 = 0
}

// ---------------------------------------------------------------------------
// Tail MLP (round-1-verified gemm + reduce)
// ---------------------------------------------------------------------------
__global__ __launch_bounds__(256)
void gemm_bf16(const bf16* __restrict__ A, int lda,
               const bf16* __restrict__ W, int ldw,
               float* __restrict__ C, int ldc,
               const float* __restrict__ bias,
               int nsplit, int kb0, int ke0, int kb1, int ke1)
{
  __shared__ __align__(16) bf16 As[128 * 64];
  __shared__ __align__(16) bf16 Bs[128 * 64];

  const int tid  = threadIdx.x;
  const int lane = tid & 63;
  const int wave = tid >> 6;
  const int m0 = blockIdx.y * 128;
  const int n0 = blockIdx.x * 128;
  const int kb = (n0 < nsplit) ? kb0 : kb1;
  const int ke = (n0 < nsplit) ? ke0 : ke1;

  int aoff[4], boff[4];
#pragma unroll
  for (int r = 0; r < 4; ++r) {
    int o16 = r * 256 + tid;
    int row = o16 >> 3;
    int sp  = o16 & 7;
    int s   = sp ^ (row & 7);
    aoff[r] = row * lda + s * 8;
    boff[r] = row * ldw + s * 8;
  }

  f32x4 acc[4][4];
#pragma unroll
  for (int i = 0; i < 4; ++i)
#pragma unroll
    for (int j = 0; j < 4; ++j) acc[i][j] = (f32x4){0.f, 0.f, 0.f, 0.f};

  const int wm = wave >> 1, wn = wave & 1;
  const int r15 = lane & 15, khalf = lane >> 4, sw = lane & 7;

  for (int kt = kb; kt < ke; kt += 64) {
    const bf16* Ag = A + (size_t)m0 * lda + kt;
    const bf16* Wg = W + (size_t)n0 * ldw + kt;
#pragma unroll
    for (int r = 0; r < 4; ++r) {
      char* la = (char*)As + (size_t)(r * 256 + wave * 64) * 16;
      char* lb = (char*)Bs + (size_t)(r * 256 + wave * 64) * 16;
      gload_lds16(Ag + aoff[r], la);
      gload_lds16(Wg + boff[r], lb);
    }
    __syncthreads();

    const bf16x8* Ald = (const bf16x8*)As;
    const bf16x8* Bld = (const bf16x8*)Bs;
#pragma unroll
    for (int kk = 0; kk < 2; ++kk) {
      bf16x8 av[4], bv[4];
#pragma unroll
      for (int i = 0; i < 4; ++i) {
        int ra = wm * 64 + i * 16 + r15;
        av[i] = Ald[ra * 8 + ((kk * 4 + khalf) ^ sw)];
        int rbw = wn * 64 + i * 16 + r15;
        bv[i] = Bld[rbw * 8 + ((kk * 4 + khalf) ^ sw)];
      }
#pragma unroll
      for (int i = 0; i < 4; ++i)
#pragma unroll
        for (int j = 0; j < 4; ++j)
          acc[i][j] = __builtin_amdgcn_mfma_f32_16x16x32_bf16(av[i], bv[j], acc[i][j], 0, 0, 0);
    }
    __syncthreads();
  }

#pragma unroll
  for (int j = 0; j < 4; ++j) {
    int colc = n0 + wn * 64 + j * 16 + r15;
    float bb = bias[colc];
#pragma unroll
    for (int i = 0; i < 4; ++i) {
      int rbase = m0 + wm * 64 + i * 16 + khalf * 4;
#pragma unroll
      for (int q = 0; q < 4; ++q)
        C[(size_t)(rbase + q) * ldc + colc] = acc[i][j][q] + bb;
    }
  }
}

__global__ void mlp_out(const float* __restrict__ Gm, const float* __restrict__ W2,
                        const float* __restrict__ b2, float* __restrict__ out)
{
  int b = blockIdx.x, l = threadIdx.x;
  float s = 0.f;
#pragma unroll
  for (int k = l; k < HID_; k += 64)
    s += fmaxf(Gm[(size_t)b * HID_ + k], 0.f) * W2[k];
#pragma unroll
  for (int off = 32; off; off >>= 1) s += __shfl_xor(s, off, 64);
  if (l == 0) out[b] = s + b2[0];
}

// ---------------------------------------------------------------------------
extern "C" void kernel_launch(void* const* d_in, const int* in_sizes, int n_in,
                              void* d_out, int out_size, void* d_ws, size_t ws_size,
                              hipStream_t stream)
{
  const float* x  = (const float*)d_in[0];
  const float* ts = (const float*)d_in[1];
  const float* Wa = (const float*)d_in[2];
  const float* ba = (const float*)d_in[3];
  const float* Ua = (const float*)d_in[4];
  const float* bu = (const float*)d_in[5];
  const float* Wd = (const float*)d_in[6];
  const float* bd = (const float*)d_in[7];
  const float* W1 = (const float*)d_in[8];
  const float* b1 = (const float*)d_in[9];
  const float* W2 = (const float*)d_in[10];
  const float* b2 = (const float*)d_in[11];

  char* ws = (char*)d_ws;
  size_t o = 0;
  auto alloc = [&](size_t bytes) {
    size_t p = o;
    o += (bytes + 255) & ~(size_t)255;
    return p;
  };
  const size_t SB = (size_t)B_ * LDA_;
  bf16*  Wimg   = (bf16*) (ws + alloc((size_t)32 * NFRAG * 512 * 2));  // 2.88 MB
  bf16*  W1b    = (bf16*) (ws + alloc((size_t)HID_ * H_ * 2));
  bf16*  states = (bf16*) (ws + alloc(SB * NBUF * 2));                 // 25.2 MB
  float* G      = (float*)(ws + alloc((size_t)B_ * HID_ * 4));         // 1 MB
  float* tsT    = (float*)(ws + alloc((size_t)B_ * T_ * 4));           // 0.8 MB
  int*   flags  = (int*)  (ws + alloc((size_t)16 * 32 * 4));

  pack_wimg<<<(32 * NFRAG * 64 + 255) / 256, 256, 0, stream>>>(Wa, Ua, Wd, Wimg);
  pack_w1<<<(HID_ * H_ + 255) / 256, 256, 0, stream>>>(W1, W1b);
  init_state<<<(B_ * LDA_ + 255) / 256, 256, 0, stream>>>(x, ts, states, tsT, flags);

  void* args[] = {(void*)&states, (void*)&x, (void*)&tsT,
                  (void*)&Wimg, (void*)&ba, (void*)&bu, (void*)&bd, (void*)&flags};
  hipLaunchCooperativeKernel((void*)persist, dim3(256), dim3(512), args, 0, stream);

  // Final state is in buffer 200 % 12 = 8 (kernel boundary makes it visible)
  gemm_bf16<<<dim3(HID_ / 128, B_ / 128), 256, 0, stream>>>(
      states + 8 * SB, LDA_, W1b, H_, G, HID_, b1, 1 << 30, 0, 512, 0, 512);
  mlp_out<<<B_, 64, 0, stream>>>(G, W2, b2, (float*)d_out);
}

// Round 16
// 2094.451 us; speedup vs baseline: 1.5483x; 1.5483x over previous
//
#include <hip/hip_runtime.h>
#include <cstdint>
#include <cstddef>

// Problem constants
#define B_   1024
#define T_   200
#define I_   64
#define H_   512
#define HID_ 256
#define LDA_ 1024   // state row: [h(512) | c(512)]  (x read direct from input)
#define NFRAG 88    // W frags per j-tile: 4 gates * 18 kk + 16 d kk
#define NBUF 12     // state rotation depth (addresses unique for 12 steps)
#define RINV 8      // acquire-inv period; NBUF >= RINV+2+skew

typedef __bf16 bf16;
typedef __bf16 bf16x8 __attribute__((ext_vector_type(8)));
typedef float  f32x4  __attribute__((ext_vector_type(4)));

__device__ inline void gload_lds16(const bf16* g, void* l) {
  void* gg = (void*)g;
  __builtin_amdgcn_global_load_lds((__attribute__((address_space(1))) void*)gg,
                                   (__attribute__((address_space(3))) void*)l,
                                   16, 0, 0);
}

__device__ inline float sigm(float x) { return 1.f / (1.f + __expf(-x)); }
__device__ inline float tanh_f(float x) {
  float e = __expf(2.f * fabsf(x));
  float r = 1.f - 2.f / (e + 1.f);
  return copysignf(r, x);
}
__device__ inline uint32_t bf16bits(float v) {
  union { bf16 h; unsigned short u; } cv; cv.h = (bf16)v; return (uint32_t)cv.u;
}

// ---------------------------------------------------------------------------
// Persistent TimeLSTM — r10's proven sync structure + r12's proven layout.
// 256 blocks x 512 threads (8 waves, 2/SIMD), 1 block/CU (90KB LDS).
// Block (mt = bid&7, jt = bid>>3): rows mt*128..+128, hidden cols jt*16..+16.
// W in LDS for all 200 steps; fp32 cell state in registers.
//
// Sync (r10, unchanged):
//  - state writes: agent-scope relaxed atomic stores (write-through to LLC)
//  - publish: __syncthreads (drains all waves' stores) then tid0 stores
//    flags[mt*32+jt] = t+1 (agent relaxed atomic)
//  - wait: wave 0 polls the 32 group flags; fence(acquire,"agent") only on
//    t%RINV==0 steps; rotation NBUF=12 > RINV+2 keeps cached reads safe.
// Layout (r12/r13/r14-proven): state rows are [h(512)|c(512)] (LDA=1024);
// x fragments are read directly from the immutable fp32 input each step.
// ---------------------------------------------------------------------------
__global__ __launch_bounds__(512, 2)
void persist(bf16* __restrict__ states,
             const float* __restrict__ x, const float* __restrict__ tsT,
             const bf16* __restrict__ img,
             const float* __restrict__ ba, const float* __restrict__ bu,
             const float* __restrict__ bd, int* __restrict__ flags)
{
  __shared__ __align__(16) bf16 Wl[NFRAG * 512];   // 90112 B

  const int tid = threadIdx.x;
  const int l   = tid & 63, w = tid >> 6;
  const int bid = blockIdx.x;
  const int mt  = bid & 7, jt = bid >> 3;
  const int m0  = mt * 128;
  const int col = l & 15, kh = l >> 4;
  const size_t SB = (size_t)B_ * LDA_;

  // Load this j-tile's W image (fragment-ordered) into LDS once.
  {
    const bf16* src = img + (size_t)jt * (NFRAG * 512);
#pragma unroll
    for (int it = 0; it < 11; ++it)    // 11 * 8192 B = 90112 B
      gload_lds16(src + it * 4096 + tid * 8, (char*)Wl + it * 8192 + tid * 16);
  }

  float bg[4], bdv;
#pragma unroll
  for (int g = 0; g < 4; ++g) {
    int n = g * 512 + jt * 16 + col;
    bg[g] = ba[n] + bu[n];
  }
  bdv = bd[jt * 16 + col];
  __syncthreads();   // drains gload_lds

  float cst[4] = {0.f, 0.f, 0.f, 0.f};   // cell state for rows kh*4+q, col
  const bf16x8* Wf = (const bf16x8*)Wl;

  int cur = 0, nxt = 1;
  for (int t = 0; t < T_; ++t) {
    const bf16* Ac = states + (size_t)cur * SB;
    bf16*       An = states + (size_t)nxt * SB;

    // --- phase A: immutable-input preloads (overlap the wait) ---
    const int rb = m0 + w * 16 + kh * 4;
    float4 tt4 = *(const float4*)(tsT + (size_t)t * B_ + rb);
    bf16x8 ax0, ax1;   // x fragments for kk=16,17 (direct from float input)
    {
      const float* xp = x + ((size_t)(m0 + w * 16 + col) * T_ + t) * I_ + kh * 8;
      float4 a0 = *(const float4*)(xp);
      float4 a1 = *(const float4*)(xp + 4);
      float4 b0 = *(const float4*)(xp + 32);
      float4 b1 = *(const float4*)(xp + 36);
      ax0 = (bf16x8){(bf16)a0.x, (bf16)a0.y, (bf16)a0.z, (bf16)a0.w,
                     (bf16)a1.x, (bf16)a1.y, (bf16)a1.z, (bf16)a1.w};
      ax1 = (bf16x8){(bf16)b0.x, (bf16)b0.y, (bf16)b0.z, (bf16)b0.w,
                     (bf16)b1.x, (bf16)b1.y, (bf16)b1.z, (bf16)b1.w};
    }

    // --- phase B: wave-0 monolithic wait + periodic fence (r10) ---
    if (t > 0) {
      if (w == 0) {
        int* fl = flags + mt * 32 + (l & 31);
        while (__hip_atomic_load(fl, __ATOMIC_RELAXED,
                                 __HIP_MEMORY_SCOPE_AGENT) < t)
          __builtin_amdgcn_s_sleep(1);
        if ((t & (RINV - 1)) == 0)
          __builtin_amdgcn_fence(__ATOMIC_ACQUIRE, "agent");  // periodic inv
        asm volatile("" ::: "memory");   // no load hoisting above the poll
      }
      __syncthreads();
    }

    // --- phase C: burst-load A row (h, c) into registers, then MFMA ---
    const size_t ra = (size_t)(m0 + w * 16 + col) * LDA_ + kh * 8;

    bf16x8 areg[32];
#pragma unroll
    for (int kk = 0; kk < 16; ++kk)
      areg[kk] = *(const bf16x8*)(Ac + ra + kk * 32);            // h
#pragma unroll
    for (int kk = 0; kk < 16; ++kk)
      areg[16 + kk] = *(const bf16x8*)(Ac + ra + 512 + kk * 32); // c

    f32x4 acc[4], accd0, accd1;
#pragma unroll
    for (int g = 0; g < 4; ++g) acc[g] = (f32x4){bg[g], bg[g], bg[g], bg[g]};
    accd0 = (f32x4){bdv, bdv, bdv, bdv};
    accd1 = (f32x4){0.f, 0.f, 0.f, 0.f};

    // gates: kk 0..15 from h, kk 16..17 from x
#pragma unroll
    for (int kk = 0; kk < 18; ++kk) {
      bf16x8 a = (kk < 16) ? areg[kk] : (kk == 16 ? ax0 : ax1);
#pragma unroll
      for (int g = 0; g < 4; ++g) {
        bf16x8 bv = Wf[(g * 18 + kk) * 64 + l];
        acc[g] = __builtin_amdgcn_mfma_f32_16x16x32_bf16(a, bv, acc[g], 0, 0, 0);
      }
    }
    // d: kk 0..15 from c, split accumulator
#pragma unroll
    for (int kk = 0; kk < 16; kk += 2) {
      accd0 = __builtin_amdgcn_mfma_f32_16x16x32_bf16(areg[16 + kk],     Wf[(72 + kk) * 64 + l], accd0, 0, 0, 0);
      accd1 = __builtin_amdgcn_mfma_f32_16x16x32_bf16(areg[16 + kk + 1], Wf[(73 + kk) * 64 + l], accd1, 0, 0, 0);
    }

    // --- phase D: gate math + packed agent-atomic state stores ---
#pragma unroll
    for (int q = 0; q < 4; ++q) {
      int row   = rb + q;
      float tt  = (&tt4.x)[q];
      float cs1 = tanh_f(accd0[q] + accd1[q]);
      float cadj = cst[q] - cs1 + cs1 * tt;
      float fg = sigm(acc[0][q]);
      float ig = sigm(acc[1][q]);
      float og = sigm(acc[2][q]);
      float cg_ = sigm(acc[3][q]);
      float cn = fg * cadj + ig * cg_;
      float hn = og * tanh_f(cn);
      cst[q] = cn;

      uint32_t hb = bf16bits(hn), cb = bf16bits(cn);
      uint32_t hb2 = (uint32_t)__shfl_xor((int)hb, 1, 64);
      uint32_t cb2 = (uint32_t)__shfl_xor((int)cb, 1, 64);
      if ((l & 1) == 0) {   // even col owns [col, col+1]
        uint32_t hwd = hb | (hb2 << 16);
        uint32_t cwd = cb | (cb2 << 16);
        uint32_t* hp = (uint32_t*)(An + (size_t)row * LDA_ + jt * 16 + col);
        uint32_t* cp = (uint32_t*)(An + (size_t)row * LDA_ + 512 + jt * 16 + col);
        __hip_atomic_store(hp, hwd, __ATOMIC_RELAXED, __HIP_MEMORY_SCOPE_AGENT);
        __hip_atomic_store(cp, cwd, __ATOMIC_RELAXED, __HIP_MEMORY_SCOPE_AGENT);
      }
    }

    // --- phase E: publish (syncthreads drains every wave's stores first) ---
    if (t + 1 < T_) {
      __syncthreads();
      if (tid == 0)
        __hip_atomic_store(flags + mt * 32 + jt, t + 1, __ATOMIC_RELAXED,
                           __HIP_MEMORY_SCOPE_AGENT);
    }

    cur = nxt;
    nxt = (nxt + 1 == NBUF) ? 0 : nxt + 1;
  }
}

// ---------------------------------------------------------------------------
// Pack W into per-j-tile images in MFMA B-fragment order.
// ---------------------------------------------------------------------------
__global__ void pack_wimg(const float* __restrict__ Wa, const float* __restrict__ Ua,
                          const float* __restrict__ Wd, bf16* __restrict__ img)
{
  int tid = blockIdx.x * 256 + threadIdx.x;   // (jt*88 + f)*64 + lane
  if (tid >= 32 * NFRAG * 64) return;
  int l  = tid & 63;
  int f  = (tid >> 6) % NFRAG;
  int jt = tid / (NFRAG * 64);
  int col = l & 15, kh = l >> 4;
  float v[8];
  if (f < 72) {
    int g = f / 18, kk = f % 18;
    int n = g * 512 + jt * 16 + col;
    if (kk < 16) {
      int k = kk * 32 + kh * 8;
#pragma unroll
      for (int r = 0; r < 8; ++r) v[r] = Wa[(size_t)n * 512 + k + r];
    } else {
      int k = (kk - 16) * 32 + kh * 8;
#pragma unroll
      for (int r = 0; r < 8; ++r) v[r] = Ua[(size_t)n * 64 + k + r];
    }
  } else {
    int kk = f - 72;
    int n = jt * 16 + col;
    int k = kk * 32 + kh * 8;
#pragma unroll
    for (int r = 0; r < 8; ++r) v[r] = Wd[(size_t)n * 512 + k + r];
  }
  bf16* dst = img + (size_t)tid * 8;
#pragma unroll
  for (int r = 0; r < 8; ++r) dst[r] = (bf16)v[r];
}

__global__ void pack_w1(const float* __restrict__ W1, bf16* __restrict__ W1b)
{
  int idx = blockIdx.x * 256 + threadIdx.x;
  if (idx < HID_ * H_) W1b[idx] = (bf16)W1[idx];
}

// init: state buf 0 (h=0, c=0), ts transpose, flag zeroing
__global__ void init_state(const float* __restrict__ x, const float* __restrict__ ts,
                           bf16* __restrict__ states, float* __restrict__ tsT,
                           int* __restrict__ flags)
{
  int idx = blockIdx.x * 256 + threadIdx.x;
  if (idx < 8 * 32) flags[idx] = 0;
  if (idx < B_ * T_) {
    int b = idx / T_, t = idx - b * T_;
    tsT[(size_t)t * B_ + b] = ts[idx];
  }
  if (idx >= B_ * LDA_) return;
  states[idx] = (bf16)0.f;   // h0 = c0 = 0
}

// ---------------------------------------------------------------------------
// Tail MLP (round-1-verified gemm + reduce)
// ---------------------------------------------------------------------------
__global__ __launch_bounds__(256)
void gemm_bf16(const bf16* __restrict__ A, int lda,
               const bf16* __restrict__ W, int ldw,
               float* __restrict__ C, int ldc,
               const float* __restrict__ bias,
               int nsplit, int kb0, int ke0, int kb1, int ke1)
{
  __shared__ __align__(16) bf16 As[128 * 64];
  __shared__ __align__(16) bf16 Bs[128 * 64];

  const int tid  = threadIdx.x;
  const int lane = tid & 63;
  const int wave = tid >> 6;
  const int m0 = blockIdx.y * 128;
  const int n0 = blockIdx.x * 128;
  const int kb = (n0 < nsplit) ? kb0 : kb1;
  const int ke = (n0 < nsplit) ? ke0 : ke1;

  int aoff[4], boff[4];
#pragma unroll
  for (int r = 0; r < 4; ++r) {
    int o16 = r * 256 + tid;
    int row = o16 >> 3;
    int sp  = o16 & 7;
    int s   = sp ^ (row & 7);
    aoff[r] = row * lda + s * 8;
    boff[r] = row * ldw + s * 8;
  }

  f32x4 acc[4][4];
#pragma unroll
  for (int i = 0; i < 4; ++i)
#pragma unroll
    for (int j = 0; j < 4; ++j) acc[i][j] = (f32x4){0.f, 0.f, 0.f, 0.f};

  const int wm = wave >> 1, wn = wave & 1;
  const int r15 = lane & 15, khalf = lane >> 4, sw = lane & 7;

  for (int kt = kb; kt < ke; kt += 64) {
    const bf16* Ag = A + (size_t)m0 * lda + kt;
    const bf16* Wg = W + (size_t)n0 * ldw + kt;
#pragma unroll
    for (int r = 0; r < 4; ++r) {
      char* la = (char*)As + (size_t)(r * 256 + wave * 64) * 16;
      char* lb = (char*)Bs + (size_t)(r * 256 + wave * 64) * 16;
      gload_lds16(Ag + aoff[r], la);
      gload_lds16(Wg + boff[r], lb);
    }
    __syncthreads();

    const bf16x8* Ald = (const bf16x8*)As;
    const bf16x8* Bld = (const bf16x8*)Bs;
#pragma unroll
    for (int kk = 0; kk < 2; ++kk) {
      bf16x8 av[4], bv[4];
#pragma unroll
      for (int i = 0; i < 4; ++i) {
        int ra = wm * 64 + i * 16 + r15;
        av[i] = Ald[ra * 8 + ((kk * 4 + khalf) ^ sw)];
        int rbw = wn * 64 + i * 16 + r15;
        bv[i] = Bld[rbw * 8 + ((kk * 4 + khalf) ^ sw)];
      }
#pragma unroll
      for (int i = 0; i < 4; ++i)
#pragma unroll
        for (int j = 0; j < 4; ++j)
          acc[i][j] = __builtin_amdgcn_mfma_f32_16x16x32_bf16(av[i], bv[j], acc[i][j], 0, 0, 0);
    }
    __syncthreads();
  }

#pragma unroll
  for (int j = 0; j < 4; ++j) {
    int colc = n0 + wn * 64 + j * 16 + r15;
    float bb = bias[colc];
#pragma unroll
    for (int i = 0; i < 4; ++i) {
      int rbase = m0 + wm * 64 + i * 16 + khalf * 4;
#pragma unroll
      for (int q = 0; q < 4; ++q)
        C[(size_t)(rbase + q) * ldc + colc] = acc[i][j][q] + bb;
    }
  }
}

__global__ void mlp_out(const float* __restrict__ Gm, const float* __restrict__ W2,
                        const float* __restrict__ b2, float* __restrict__ out)
{
  int b = blockIdx.x, l = threadIdx.x;
  float s = 0.f;
#pragma unroll
  for (int k = l; k < HID_; k += 64)
    s += fmaxf(Gm[(size_t)b * HID_ + k], 0.f) * W2[k];
#pragma unroll
  for (int off = 32; off; off >>= 1) s += __shfl_xor(s, off, 64);
  if (l == 0) out[b] = s + b2[0];
}

// ---------------------------------------------------------------------------
extern "C" void kernel_launch(void* const* d_in, const int* in_sizes, int n_in,
                              void* d_out, int out_size, void* d_ws, size_t ws_size,
                              hipStream_t stream)
{
  const float* x  = (const float*)d_in[0];
  const float* ts = (const float*)d_in[1];
  const float* Wa = (const float*)d_in[2];
  const float* ba = (const float*)d_in[3];
  const float* Ua = (const float*)d_in[4];
  const float* bu = (const float*)d_in[5];
  const float* Wd = (const float*)d_in[6];
  const float* bd = (const float*)d_in[7];
  const float* W1 = (const float*)d_in[8];
  const float* b1 = (const float*)d_in[9];
  const float* W2 = (const float*)d_in[10];
  const float* b2 = (const float*)d_in[11];

  char* ws = (char*)d_ws;
  size_t o = 0;
  auto alloc = [&](size_t bytes) {
    size_t p = o;
    o += (bytes + 255) & ~(size_t)255;
    return p;
  };
  const size_t SB = (size_t)B_ * LDA_;
  bf16*  Wimg   = (bf16*) (ws + alloc((size_t)32 * NFRAG * 512 * 2));  // 2.88 MB
  bf16*  W1b    = (bf16*) (ws + alloc((size_t)HID_ * H_ * 2));
  bf16*  states = (bf16*) (ws + alloc(SB * NBUF * 2));                 // 25.2 MB
  float* G      = (float*)(ws + alloc((size_t)B_ * HID_ * 4));         // 1 MB
  float* tsT    = (float*)(ws + alloc((size_t)B_ * T_ * 4));           // 0.8 MB
  int*   flags  = (int*)  (ws + alloc((size_t)8 * 32 * 4));

  pack_wimg<<<(32 * NFRAG * 64 + 255) / 256, 256, 0, stream>>>(Wa, Ua, Wd, Wimg);
  pack_w1<<<(HID_ * H_ + 255) / 256, 256, 0, stream>>>(W1, W1b);
  init_state<<<(B_ * LDA_ + 255) / 256, 256, 0, stream>>>(x, ts, states, tsT, flags);

  void* args[] = {(void*)&states, (void*)&x, (void*)&tsT,
                  (void*)&Wimg, (void*)&ba, (void*)&bu, (void*)&bd, (void*)&flags};
  hipLaunchCooperativeKernel((void*)persist, dim3(256), dim3(512), args, 0, stream);

  // Final state is in buffer 200 % 12 = 8 (kernel boundary makes it visible)
  gemm_bf16<<<dim3(HID_ / 128, B_ / 128), 256, 0, stream>>>(
      states + 8 * SB, LDA_, W1b, H_, G, HID_, b1, 1 << 30, 0, 512, 0, 512);
  mlp_out<<<B_, 64, 0, stream>>>(G, W2, b2, (float*)d_out);
}

// Round 17
// 1966.911 us; speedup vs baseline: 1.6487x; 1.0648x over previous
//
#include <hip/hip_runtime.h>
#include <cstdint>
#include <cstddef>

// Problem constants
#define B_   1024
#define T_   200
#define I_   64
#define H_   512
#define HID_ 256
#define LDA_ 1024   // state row: [h(512) | c(512)]  (x read direct from input)
#define NFRAG 88    // W frags per j-tile: 4 gates * 18 kk + 16 d kk
#define NBUF 12     // state rotation depth (addresses unique for 12 steps)
#define RINV 8      // acquire-inv period; NBUF >= RINV+2+skew
#define FPAD 32     // ints per flag (128B = one cache line each)

typedef __bf16 bf16;
typedef __bf16 bf16x8 __attribute__((ext_vector_type(8)));
typedef float  f32x4  __attribute__((ext_vector_type(4)));

__device__ inline void gload_lds16(const bf16* g, void* l) {
  void* gg = (void*)g;
  __builtin_amdgcn_global_load_lds((__attribute__((address_space(1))) void*)gg,
                                   (__attribute__((address_space(3))) void*)l,
                                   16, 0, 0);
}

__device__ inline float sigm(float x) { return 1.f / (1.f + __expf(-x)); }
__device__ inline float tanh_f(float x) {
  float e = __expf(2.f * fabsf(x));
  float r = 1.f - 2.f / (e + 1.f);
  return copysignf(r, x);
}
__device__ inline uint32_t bf16bits(float v) {
  union { bf16 h; unsigned short u; } cv; cv.h = (bf16)v; return (uint32_t)cv.u;
}

// ---------------------------------------------------------------------------
// Persistent TimeLSTM — r16 (r10 sync + [h|c] layout) with PADDED FLAGS:
// each flag in its own 128B cache line so the LLC serves the 32 producer
// stores and 256 poller lanes from independent lines (no same-line
// serialization). Sync semantics byte-identical to r10/r16:
//  - state writes: agent-scope relaxed atomic stores (write-through to LLC)
//  - publish: __syncthreads (drains all waves' stores) then tid0 stores
//    flags[(mt*32+jt)*FPAD] = t+1 (agent relaxed atomic)
//  - wait: wave 0 polls the 32 group flags (one line per lane);
//    fence(acquire,"agent") only on t%RINV==0 steps; rotation NBUF=12
//    > RINV+2 keeps cached state reads safe.
// 256 blocks x 512 threads (8 waves, 2/SIMD), 1 block/CU (90KB LDS).
// Block (mt = bid&7, jt = bid>>3): rows mt*128..+128, hidden cols jt*16..+16.
// W in LDS for all 200 steps; fp32 cell state in registers.
// ---------------------------------------------------------------------------
__global__ __launch_bounds__(512, 2)
void persist(bf16* __restrict__ states,
             const float* __restrict__ x, const float* __restrict__ tsT,
             const bf16* __restrict__ img,
             const float* __restrict__ ba, const float* __restrict__ bu,
             const float* __restrict__ bd, int* __restrict__ flags)
{
  __shared__ __align__(16) bf16 Wl[NFRAG * 512];   // 90112 B

  const int tid = threadIdx.x;
  const int l   = tid & 63, w = tid >> 6;
  const int bid = blockIdx.x;
  const int mt  = bid & 7, jt = bid >> 3;
  const int m0  = mt * 128;
  const int col = l & 15, kh = l >> 4;
  const size_t SB = (size_t)B_ * LDA_;

  // Load this j-tile's W image (fragment-ordered) into LDS once.
  {
    const bf16* src = img + (size_t)jt * (NFRAG * 512);
#pragma unroll
    for (int it = 0; it < 11; ++it)    // 11 * 8192 B = 90112 B
      gload_lds16(src + it * 4096 + tid * 8, (char*)Wl + it * 8192 + tid * 16);
  }

  float bg[4], bdv;
#pragma unroll
  for (int g = 0; g < 4; ++g) {
    int n = g * 512 + jt * 16 + col;
    bg[g] = ba[n] + bu[n];
  }
  bdv = bd[jt * 16 + col];
  __syncthreads();   // drains gload_lds

  float cst[4] = {0.f, 0.f, 0.f, 0.f};   // cell state for rows kh*4+q, col
  const bf16x8* Wf = (const bf16x8*)Wl;

  int cur = 0, nxt = 1;
  for (int t = 0; t < T_; ++t) {
    const bf16* Ac = states + (size_t)cur * SB;
    bf16*       An = states + (size_t)nxt * SB;

    // --- phase A: immutable-input preloads (overlap the wait) ---
    const int rb = m0 + w * 16 + kh * 4;
    float4 tt4 = *(const float4*)(tsT + (size_t)t * B_ + rb);
    bf16x8 ax0, ax1;   // x fragments for kk=16,17 (direct from float input)
    {
      const float* xp = x + ((size_t)(m0 + w * 16 + col) * T_ + t) * I_ + kh * 8;
      float4 a0 = *(const float4*)(xp);
      float4 a1 = *(const float4*)(xp + 4);
      float4 b0 = *(const float4*)(xp + 32);
      float4 b1 = *(const float4*)(xp + 36);
      ax0 = (bf16x8){(bf16)a0.x, (bf16)a0.y, (bf16)a0.z, (bf16)a0.w,
                     (bf16)a1.x, (bf16)a1.y, (bf16)a1.z, (bf16)a1.w};
      ax1 = (bf16x8){(bf16)b0.x, (bf16)b0.y, (bf16)b0.z, (bf16)b0.w,
                     (bf16)b1.x, (bf16)b1.y, (bf16)b1.z, (bf16)b1.w};
    }

    // --- phase B: wave-0 monolithic wait + periodic fence (r10) ---
    if (t > 0) {
      if (w == 0) {
        int* fl = flags + ((mt * 32 + (l & 31)) * FPAD);
        while (__hip_atomic_load(fl, __ATOMIC_RELAXED,
                                 __HIP_MEMORY_SCOPE_AGENT) < t)
          __builtin_amdgcn_s_sleep(1);
        if ((t & (RINV - 1)) == 0)
          __builtin_amdgcn_fence(__ATOMIC_ACQUIRE, "agent");  // periodic inv
        asm volatile("" ::: "memory");   // no load hoisting above the poll
      }
      __syncthreads();
    }

    // --- phase C: burst-load A row (h, c) into registers, then MFMA ---
    const size_t ra = (size_t)(m0 + w * 16 + col) * LDA_ + kh * 8;

    bf16x8 areg[32];
#pragma unroll
    for (int kk = 0; kk < 16; ++kk)
      areg[kk] = *(const bf16x8*)(Ac + ra + kk * 32);            // h
#pragma unroll
    for (int kk = 0; kk < 16; ++kk)
      areg[16 + kk] = *(const bf16x8*)(Ac + ra + 512 + kk * 32); // c

    f32x4 acc[4], accd0, accd1;
#pragma unroll
    for (int g = 0; g < 4; ++g) acc[g] = (f32x4){bg[g], bg[g], bg[g], bg[g]};
    accd0 = (f32x4){bdv, bdv, bdv, bdv};
    accd1 = (f32x4){0.f, 0.f, 0.f, 0.f};

    // gates: kk 0..15 from h, kk 16..17 from x
#pragma unroll
    for (int kk = 0; kk < 18; ++kk) {
      bf16x8 a = (kk < 16) ? areg[kk] : (kk == 16 ? ax0 : ax1);
#pragma unroll
      for (int g = 0; g < 4; ++g) {
        bf16x8 bv = Wf[(g * 18 + kk) * 64 + l];
        acc[g] = __builtin_amdgcn_mfma_f32_16x16x32_bf16(a, bv, acc[g], 0, 0, 0);
      }
    }
    // d: kk 0..15 from c, split accumulator
#pragma unroll
    for (int kk = 0; kk < 16; kk += 2) {
      accd0 = __builtin_amdgcn_mfma_f32_16x16x32_bf16(areg[16 + kk],     Wf[(72 + kk) * 64 + l], accd0, 0, 0, 0);
      accd1 = __builtin_amdgcn_mfma_f32_16x16x32_bf16(areg[16 + kk + 1], Wf[(73 + kk) * 64 + l], accd1, 0, 0, 0);
    }

    // --- phase D: gate math + packed agent-atomic state stores ---
#pragma unroll
    for (int q = 0; q < 4; ++q) {
      int row   = rb + q;
      float tt  = (&tt4.x)[q];
      float cs1 = tanh_f(accd0[q] + accd1[q]);
      float cadj = cst[q] - cs1 + cs1 * tt;
      float fg = sigm(acc[0][q]);
      float ig = sigm(acc[1][q]);
      float og = sigm(acc[2][q]);
      float cg_ = sigm(acc[3][q]);
      float cn = fg * cadj + ig * cg_;
      float hn = og * tanh_f(cn);
      cst[q] = cn;

      uint32_t hb = bf16bits(hn), cb = bf16bits(cn);
      uint32_t hb2 = (uint32_t)__shfl_xor((int)hb, 1, 64);
      uint32_t cb2 = (uint32_t)__shfl_xor((int)cb, 1, 64);
      if ((l & 1) == 0) {   // even col owns [col, col+1]
        uint32_t hwd = hb | (hb2 << 16);
        uint32_t cwd = cb | (cb2 << 16);
        uint32_t* hp = (uint32_t*)(An + (size_t)row * LDA_ + jt * 16 + col);
        uint32_t* cp = (uint32_t*)(An + (size_t)row * LDA_ + 512 + jt * 16 + col);
        __hip_atomic_store(hp, hwd, __ATOMIC_RELAXED, __HIP_MEMORY_SCOPE_AGENT);
        __hip_atomic_store(cp, cwd, __ATOMIC_RELAXED, __HIP_MEMORY_SCOPE_AGENT);
      }
    }

    // --- phase E: publish (syncthreads drains every wave's stores first) ---
    if (t + 1 < T_) {
      __syncthreads();
      if (tid == 0)
        __hip_atomic_store(flags + ((mt * 32 + jt) * FPAD), t + 1,
                           __ATOMIC_RELAXED, __HIP_MEMORY_SCOPE_AGENT);
    }

    cur = nxt;
    nxt = (nxt + 1 == NBUF) ? 0 : nxt + 1;
  }
}

// ---------------------------------------------------------------------------
// Pack W into per-j-tile images in MFMA B-fragment order.
// ---------------------------------------------------------------------------
__global__ void pack_wimg(const float* __restrict__ Wa, const float* __restrict__ Ua,
                          const float* __restrict__ Wd, bf16* __restrict__ img)
{
  int tid = blockIdx.x * 256 + threadIdx.x;   // (jt*88 + f)*64 + lane
  if (tid >= 32 * NFRAG * 64) return;
  int l  = tid & 63;
  int f  = (tid >> 6) % NFRAG;
  int jt = tid / (NFRAG * 64);
  int col = l & 15, kh = l >> 4;
  float v[8];
  if (f < 72) {
    int g = f / 18, kk = f % 18;
    int n = g * 512 + jt * 16 + col;
    if (kk < 16) {
      int k = kk * 32 + kh * 8;
#pragma unroll
      for (int r = 0; r < 8; ++r) v[r] = Wa[(size_t)n * 512 + k + r];
    } else {
      int k = (kk - 16) * 32 + kh * 8;
#pragma unroll
      for (int r = 0; r < 8; ++r) v[r] = Ua[(size_t)n * 64 + k + r];
    }
  } else {
    int kk = f - 72;
    int n = jt * 16 + col;
    int k = kk * 32 + kh * 8;
#pragma unroll
    for (int r = 0; r < 8; ++r) v[r] = Wd[(size_t)n * 512 + k + r];
  }
  bf16* dst = img + (size_t)tid * 8;
#pragma unroll
  for (int r = 0; r < 8; ++r) dst[r] = (bf16)v[r];
}

__global__ void pack_w1(const float* __restrict__ W1, bf16* __restrict__ W1b)
{
  int idx = blockIdx.x * 256 + threadIdx.x;
  if (idx < HID_ * H_) W1b[idx] = (bf16)W1[idx];
}

// init: state buf 0 (h=0, c=0), ts transpose, flag zeroing
__global__ void init_state(const float* __restrict__ x, const float* __restrict__ ts,
                           bf16* __restrict__ states, float* __restrict__ tsT,
                           int* __restrict__ flags)
{
  int idx = blockIdx.x * 256 + threadIdx.x;
  if (idx < 8 * 32 * FPAD) flags[idx] = 0;
  if (idx < B_ * T_) {
    int b = idx / T_, t = idx - b * T_;
    tsT[(size_t)t * B_ + b] = ts[idx];
  }
  if (idx >= B_ * LDA_) return;
  states[idx] = (bf16)0.f;   // h0 = c0 = 0
}

// ---------------------------------------------------------------------------
// Tail MLP (round-1-verified gemm + reduce)
// ---------------------------------------------------------------------------
__global__ __launch_bounds__(256)
void gemm_bf16(const bf16* __restrict__ A, int lda,
               const bf16* __restrict__ W, int ldw,
               float* __restrict__ C, int ldc,
               const float* __restrict__ bias,
               int nsplit, int kb0, int ke0, int kb1, int ke1)
{
  __shared__ __align__(16) bf16 As[128 * 64];
  __shared__ __align__(16) bf16 Bs[128 * 64];

  const int tid  = threadIdx.x;
  const int lane = tid & 63;
  const int wave = tid >> 6;
  const int m0 = blockIdx.y * 128;
  const int n0 = blockIdx.x * 128;
  const int kb = (n0 < nsplit) ? kb0 : kb1;
  const int ke = (n0 < nsplit) ? ke0 : ke1;

  int aoff[4], boff[4];
#pragma unroll
  for (int r = 0; r < 4; ++r) {
    int o16 = r * 256 + tid;
    int row = o16 >> 3;
    int sp  = o16 & 7;
    int s   = sp ^ (row & 7);
    aoff[r] = row * lda + s * 8;
    boff[r] = row * ldw + s * 8;
  }

  f32x4 acc[4][4];
#pragma unroll
  for (int i = 0; i < 4; ++i)
#pragma unroll
    for (int j = 0; j < 4; ++j) acc[i][j] = (f32x4){0.f, 0.f, 0.f, 0.f};

  const int wm = wave >> 1, wn = wave & 1;
  const int r15 = lane & 15, khalf = lane >> 4, sw = lane & 7;

  for (int kt = kb; kt < ke; kt += 64) {
    const bf16* Ag = A + (size_t)m0 * lda + kt;
    const bf16* Wg = W + (size_t)n0 * ldw + kt;
#pragma unroll
    for (int r = 0; r < 4; ++r) {
      char* la = (char*)As + (size_t)(r * 256 + wave * 64) * 16;
      char* lb = (char*)Bs + (size_t)(r * 256 + wave * 64) * 16;
      gload_lds16(Ag + aoff[r], la);
      gload_lds16(Wg + boff[r], lb);
    }
    __syncthreads();

    const bf16x8* Ald = (const bf16x8*)As;
    const bf16x8* Bld = (const bf16x8*)Bs;
#pragma unroll
    for (int kk = 0; kk < 2; ++kk) {
      bf16x8 av[4], bv[4];
#pragma unroll
      for (int i = 0; i < 4; ++i) {
        int ra = wm * 64 + i * 16 + r15;
        av[i] = Ald[ra * 8 + ((kk * 4 + khalf) ^ sw)];
        int rbw = wn * 64 + i * 16 + r15;
        bv[i] = Bld[rbw * 8 + ((kk * 4 + khalf) ^ sw)];
      }
#pragma unroll
      for (int i = 0; i < 4; ++i)
#pragma unroll
        for (int j = 0; j < 4; ++j)
          acc[i][j] = __builtin_amdgcn_mfma_f32_16x16x32_bf16(av[i], bv[j], acc[i][j], 0, 0, 0);
    }
    __syncthreads();
  }

#pragma unroll
  for (int j = 0; j < 4; ++j) {
    int colc = n0 + wn * 64 + j * 16 + r15;
    float bb = bias[colc];
#pragma unroll
    for (int i = 0; i < 4; ++i) {
      int rbase = m0 + wm * 64 + i * 16 + khalf * 4;
#pragma unroll
      for (int q = 0; q < 4; ++q)
        C[(size_t)(rbase + q) * ldc + colc] = acc[i][j][q] + bb;
    }
  }
}

__global__ void mlp_out(const float* __restrict__ Gm, const float* __restrict__ W2,
                        const float* __restrict__ b2, float* __restrict__ out)
{
  int b = blockIdx.x, l = threadIdx.x;
  float s = 0.f;
#pragma unroll
  for (int k = l; k < HID_; k += 64)
    s += fmaxf(Gm[(size_t)b * HID_ + k], 0.f) * W2[k];
#pragma unroll
  for (int off = 32; off; off >>= 1) s += __shfl_xor(s, off, 64);
  if (l == 0) out[b] = s + b2[0];
}

// ---------------------------------------------------------------------------
extern "C" void kernel_launch(void* const* d_in, const int* in_sizes, int n_in,
                              void* d_out, int out_size, void* d_ws, size_t ws_size,
                              hipStream_t stream)
{
  const float* x  = (const float*)d_in[0];
  const float* ts = (const float*)d_in[1];
  const float* Wa = (const float*)d_in[2];
  const float* ba = (const float*)d_in[3];
  const float* Ua = (const float*)d_in[4];
  const float* bu = (const float*)d_in[5];
  const float* Wd = (const float*)d_in[6];
  const float* bd = (const float*)d_in[7];
  const float* W1 = (const float*)d_in[8];
  const float* b1 = (const float*)d_in[9];
  const float* W2 = (const float*)d_in[10];
  const float* b2 = (const float*)d_in[11];

  char* ws = (char*)d_ws;
  size_t o = 0;
  auto alloc = [&](size_t bytes) {
    size_t p = o;
    o += (bytes + 255) & ~(size_t)255;
    return p;
  };
  const size_t SB = (size_t)B_ * LDA_;
  bf16*  Wimg   = (bf16*) (ws + alloc((size_t)32 * NFRAG * 512 * 2));  // 2.88 MB
  bf16*  W1b    = (bf16*) (ws + alloc((size_t)HID_ * H_ * 2));
  bf16*  states = (bf16*) (ws + alloc(SB * NBUF * 2));                 // 25.2 MB
  float* G      = (float*)(ws + alloc((size_t)B_ * HID_ * 4));         // 1 MB
  float* tsT    = (float*)(ws + alloc((size_t)B_ * T_ * 4));           // 0.8 MB
  int*   flags  = (int*)  (ws + alloc((size_t)8 * 32 * FPAD * 4));     // 32 KB

  pack_wimg<<<(32 * NFRAG * 64 + 255) / 256, 256, 0, stream>>>(Wa, Ua, Wd, Wimg);
  pack_w1<<<(HID_ * H_ + 255) / 256, 256, 0, stream>>>(W1, W1b);
  init_state<<<(B_ * LDA_ + 255) / 256, 256, 0, stream>>>(x, ts, states, tsT, flags);

  void* args[] = {(void*)&states, (void*)&x, (void*)&tsT,
                  (void*)&Wimg, (void*)&ba, (void*)&bu, (void*)&bd, (void*)&flags};
  hipLaunchCooperativeKernel((void*)persist, dim3(256), dim3(512), args, 0, stream);

  // Final state is in buffer 200 % 12 = 8 (kernel boundary makes it visible)
  gemm_bf16<<<dim3(HID_ / 128, B_ / 128), 256, 0, stream>>>(
      states + 8 * SB, LDA_, W1b, H_, G, HID_, b1, 1 << 30, 0, 512, 0, 512);
  mlp_out<<<B_, 64, 0, stream>>>(G, W2, b2, (float*)d_out);
}